// Round 11
// baseline (255.142 us; speedup 1.0000x reference)
//
#include <hip/hip_runtime.h>
#include <hip/hip_fp16.h>
#include <math.h>

#define N_NODES 65536
#define N_EDGES 1048576
#define HDIM 64
#define NCLS 10
#define NGRAPH 256
#define NLAYER 3
#define BN_EPS 1e-5f
#define NBUCKET 256     // nodes per bucket = 256, bucket = dst >> 8
#define NPBLK 256       // pass-1 blocks; edges per block = 4096

// ---------------- pass 1a: per-block bucket histogram ----------------

__global__ __launch_bounds__(256) void hist_kernel(const int* __restrict__ dst,
                                                   unsigned* __restrict__ bhist) {
    __shared__ unsigned hist[NBUCKET];
    int b = blockIdx.x, tid = threadIdx.x;
    hist[tid] = 0;
    __syncthreads();
    int base = b * 4096;
#pragma unroll
    for (int k = 0; k < 16; ++k) {
        int d = dst[base + k * 256 + tid];
        atomicAdd(&hist[d >> 8], 1u);
    }
    __syncthreads();
    bhist[tid * NPBLK + b] = hist[tid];  // bucket-major for lexicographic scan
}

// ---------------- pass 1b: exclusive scan over 64K (bucket, block) counts ----------------

__global__ __launch_bounds__(256) void scan1_kernel(const unsigned* __restrict__ in,
                                                    unsigned* __restrict__ out,
                                                    unsigned* __restrict__ bsum) {
    __shared__ unsigned lds[256];
    int t = threadIdx.x, b = blockIdx.x;
    unsigned v = in[b * 256 + t];
    lds[t] = v;
    __syncthreads();
#pragma unroll
    for (int off = 1; off < 256; off <<= 1) {
        unsigned add = (t >= off) ? lds[t - off] : 0u;
        __syncthreads();
        lds[t] += add;
        __syncthreads();
    }
    out[b * 256 + t] = lds[t] - v;  // exclusive within block
    if (t == 255) bsum[b] = lds[255];
}

// scan2 + BN-affine precompute fused (both tiny single-block work)
__global__ __launch_bounds__(256) void scan2_kernel(const unsigned* __restrict__ bsum,
                                                    unsigned* __restrict__ carry,
                                                    const float* __restrict__ bias,
                                                    const float* __restrict__ gamma,
                                                    const float* __restrict__ beta,
                                                    const float* __restrict__ mean,
                                                    const float* __restrict__ var,
                                                    float* __restrict__ scb,
                                                    float* __restrict__ shb) {
    __shared__ unsigned lds[256];
    int t = threadIdx.x;
    unsigned v = bsum[t];
    lds[t] = v;
    __syncthreads();
#pragma unroll
    for (int off = 1; off < 256; off <<= 1) {
        unsigned add = (t >= off) ? lds[t - off] : 0u;
        __syncthreads();
        lds[t] += add;
        __syncthreads();
    }
    carry[t] = lds[t] - v;  // exclusive
    if (t < NLAYER * HDIM) {
        float sc = gamma[t] * rsqrtf(var[t] + BN_EPS);
        scb[t] = sc;
        shb[t] = (bias[t] - mean[t]) * sc + beta[t];
    }
}

// ---------------- pass 1c: partition edges into coarse buckets (packed 16+16) ----------------

__global__ __launch_bounds__(256) void partition_kernel(const int* __restrict__ ei,
                                                        const unsigned* __restrict__ bpos,
                                                        const unsigned* __restrict__ carry,
                                                        unsigned* __restrict__ ebuf) {
    __shared__ unsigned cur[NBUCKET];
    int b = blockIdx.x, tid = threadIdx.x;
    // global index of (bucket=tid, block=b) is tid*NPBLK+b; its carry block is tid
    cur[tid] = bpos[tid * NPBLK + b] + carry[tid];
    __syncthreads();
    int base = b * 4096;
#pragma unroll
    for (int k = 0; k < 16; ++k) {
        int e = base + k * 256 + tid;
        int s = ei[e];
        int d = ei[N_EDGES + e];
        unsigned slot = atomicAdd(&cur[d >> 8], 1u);
        ebuf[slot] = ((unsigned)d << 16) | (unsigned)s;
    }
}

// ---------------- pass 2: per-bucket exact CSR (block-private window) ----------------

__global__ __launch_bounds__(256) void csr_kernel(const unsigned* __restrict__ ebuf,
                                                  const unsigned* __restrict__ bpos,
                                                  const unsigned* __restrict__ carry,
                                                  unsigned* __restrict__ offsets,
                                                  float* __restrict__ dis,
                                                  unsigned short* __restrict__ srcs) {
    __shared__ unsigned hist[NBUCKET];
    __shared__ unsigned scn[NBUCKET];
    int B = blockIdx.x, tid = threadIdx.x;
    unsigned start = bpos[B * NPBLK] + carry[B];
    unsigned end = (B == NBUCKET - 1) ? N_EDGES : (bpos[(B + 1) * NPBLK] + carry[B + 1]);
    hist[tid] = 0;
    __syncthreads();
    for (unsigned e = start + tid; e < end; e += 256)
        atomicAdd(&hist[(ebuf[e] >> 16) & 255], 1u);
    __syncthreads();
    unsigned v = hist[tid];
    scn[tid] = v;
    __syncthreads();
#pragma unroll
    for (int off = 1; off < 256; off <<= 1) {
        unsigned add = (tid >= off) ? scn[tid - off] : 0u;
        __syncthreads();
        scn[tid] += add;
        __syncthreads();
    }
    unsigned gbase = start + scn[tid] - v;  // global CSR base for local node tid
    int node = B * 256 + tid;
    offsets[node] = gbase;
    dis[node] = rsqrtf((float)(v + 1u));
    if (B == NBUCKET - 1 && tid == 255) offsets[N_NODES] = N_EDGES;
    hist[tid] = gbase;  // reuse as global-slot cursor
    __syncthreads();
    for (unsigned e = start + tid; e < end; e += 256) {
        unsigned ed = ebuf[e];
        unsigned slot = atomicAdd(&hist[(ed >> 16) & 255], 1u);
        srcs[slot] = (unsigned short)(ed & 0xFFFFu);
    }
}

// ---------------- GEMM: hw16[n] = fp16((h @ W)[n] * dis[n]) ----------------

__global__ __launch_bounds__(256) void gemm_kernel(const float* __restrict__ hin,
                                                   const float* __restrict__ W,
                                                   const float* __restrict__ dis,
                                                   __half* __restrict__ hw16) {
    __shared__ float hs[64][68];
    __shared__ float ws[64 * 64];
    int tid = threadIdx.x;
    int row0 = blockIdx.x * 64;

    {
        const float4* Wv = (const float4*)W;
        float4* wsv = (float4*)ws;
#pragma unroll
        for (int i = 0; i < 4; ++i) wsv[tid + i * 256] = Wv[tid + i * 256];
    }
    {
        const float4* Hv = (const float4*)(hin + (size_t)row0 * HDIM);
#pragma unroll
        for (int i = 0; i < 4; ++i) {
            int idx = tid + i * 256;
            int r = idx >> 4;
            int c = (idx & 15) << 2;
            *(float4*)&hs[r][c] = Hv[idx];
        }
    }
    __syncthreads();

    int tx = tid & 15, ty = tid >> 4;
    float acc[4][4] = {};
#pragma unroll
    for (int kq = 0; kq < 16; ++kq) {
        int k = kq * 4;
        float4 a[4], b[4];
#pragma unroll
        for (int i = 0; i < 4; ++i) a[i] = *(const float4*)&hs[ty * 4 + i][k];
#pragma unroll
        for (int kk = 0; kk < 4; ++kk) b[kk] = *(const float4*)&ws[(k + kk) * 64 + tx * 4];
#pragma unroll
        for (int kk = 0; kk < 4; ++kk) {
            float b0 = b[kk].x, b1 = b[kk].y, b2 = b[kk].z, b3 = b[kk].w;
#pragma unroll
            for (int i = 0; i < 4; ++i) {
                float av = (kk == 0) ? a[i].x : (kk == 1) ? a[i].y : (kk == 2) ? a[i].z : a[i].w;
                acc[i][0] += av * b0;
                acc[i][1] += av * b1;
                acc[i][2] += av * b2;
                acc[i][3] += av * b3;
            }
        }
    }

#pragma unroll
    for (int i = 0; i < 4; ++i) {
        int row = row0 + ty * 4 + i;
        float dd = dis[row];
        __half2 pa = __floats2half2_rn(acc[i][0] * dd, acc[i][1] * dd);
        __half2 pb = __floats2half2_rn(acc[i][2] * dd, acc[i][3] * dd);
        uint2 pk;
        pk.x = *(unsigned*)&pa;
        pk.y = *(unsigned*)&pb;
        *(uint2*)&hw16[(size_t)row * HDIM + tx * 4] = pk;
    }
}

// ---------------- aggregate + epilogue, feature-split (blockIdx.y = half) ----------------
// Per pass: gather 64B half-rows -> working set 4 MiB = one XCD L2.
// one wave per node; lanes = 16 edge-slots x 4 feature lanes (uint4 = 8 features each).

__global__ __launch_bounds__(256) void aggregate_kernel(const __half* __restrict__ hw16,
                                                        const float* __restrict__ dis,
                                                        const unsigned* __restrict__ offsets,
                                                        const unsigned short* __restrict__ srcs,
                                                        const float* __restrict__ scb,
                                                        const float* __restrict__ shb,
                                                        float* __restrict__ h,
                                                        int has_res) {
    int n = (blockIdx.x * 256 + threadIdx.x) >> 6;
    int lane = threadIdx.x & 63;
    int pass = blockIdx.y;          // 0: features 0..31, 1: features 32..63
    int eslot = lane >> 2;          // 0..15
    int fl = lane & 3;              // uint4 within the 64B half-row
    int hbase = pass * 4 + fl;      // uint4 index within the 128B full row (8 per row)
    int e0 = (int)offsets[n];
    int e1 = (int)offsets[n + 1];

    const uint4* hv = (const uint4*)hw16;

    float4 accA = make_float4(0.f, 0.f, 0.f, 0.f);
    float4 accB = make_float4(0.f, 0.f, 0.f, 0.f);
    for (int e = e0 + eslot; e < e1; e += 16) {
        int s0 = srcs[e];
        uint4 r0 = hv[(size_t)s0 * 8 + hbase];
        float2 p0 = __half22float2(*(__half2*)&r0.x);
        float2 p1 = __half22float2(*(__half2*)&r0.y);
        float2 p2 = __half22float2(*(__half2*)&r0.z);
        float2 p3 = __half22float2(*(__half2*)&r0.w);
        accA.x += p0.x; accA.y += p0.y; accA.z += p1.x; accA.w += p1.y;
        accB.x += p2.x; accB.y += p2.y; accB.z += p3.x; accB.w += p3.y;
    }
    // reduce across the 16 edge slots (lane xor 4, 8, 16, 32)
#pragma unroll
    for (int m = 4; m <= 32; m <<= 1) {
        accA.x += __shfl_xor(accA.x, m); accA.y += __shfl_xor(accA.y, m);
        accA.z += __shfl_xor(accA.z, m); accA.w += __shfl_xor(accA.w, m);
        accB.x += __shfl_xor(accB.x, m); accB.y += __shfl_xor(accB.y, m);
        accB.z += __shfl_xor(accB.z, m); accB.w += __shfl_xor(accB.w, m);
    }
    if (lane < 4) {
        // self-loop: + own half-row (hw16 already carries one dis factor)
        uint4 rs = hv[(size_t)n * 8 + hbase];
        float2 p0 = __half22float2(*(__half2*)&rs.x);
        float2 p1 = __half22float2(*(__half2*)&rs.y);
        float2 p2 = __half22float2(*(__half2*)&rs.z);
        float2 p3 = __half22float2(*(__half2*)&rs.w);
        accA.x += p0.x; accA.y += p0.y; accA.z += p1.x; accA.w += p1.y;
        accB.x += p2.x; accB.y += p2.y; accB.z += p3.x; accB.w += p3.y;
        float d = dis[n];
        int off = pass * 32 + fl * 8;   // feature offset within the node row
        float4 scA = *(const float4*)&scb[off];
        float4 scB = *(const float4*)&scb[off + 4];
        float4 shA = *(const float4*)&shb[off];
        float4 shB = *(const float4*)&shb[off + 4];
        float o0 = fmaxf(accA.x * d * scA.x + shA.x, 0.0f);
        float o1 = fmaxf(accA.y * d * scA.y + shA.y, 0.0f);
        float o2 = fmaxf(accA.z * d * scA.z + shA.z, 0.0f);
        float o3 = fmaxf(accA.w * d * scA.w + shA.w, 0.0f);
        float o4 = fmaxf(accB.x * d * scB.x + shB.x, 0.0f);
        float o5 = fmaxf(accB.y * d * scB.y + shB.y, 0.0f);
        float o6 = fmaxf(accB.z * d * scB.z + shB.z, 0.0f);
        float o7 = fmaxf(accB.w * d * scB.w + shB.w, 0.0f);
        float* hp = &h[(size_t)n * HDIM + off];
        if (has_res) {
            float4 rA = *(const float4*)hp;
            float4 rB = *(const float4*)(hp + 4);
            o0 += rA.x; o1 += rA.y; o2 += rA.z; o3 += rA.w;
            o4 += rB.x; o5 += rB.y; o6 += rB.z; o7 += rB.w;
        }
        *(float4*)hp = make_float4(o0, o1, o2, o3);
        *(float4*)(hp + 4) = make_float4(o4, o5, o6, o7);
    }
}

// ---------------- fused global mean pool + classifier ----------------

__device__ __forceinline__ int lower_bound_batch(const int* __restrict__ batch, int val) {
    int lo = 0, hi = N_NODES;
    while (lo < hi) {
        int mid = (lo + hi) >> 1;
        if (batch[mid] < val) lo = mid + 1; else hi = mid;
    }
    return lo;
}

__global__ __launch_bounds__(256) void pool_classify_kernel(const float* __restrict__ h,
                                                            const int* __restrict__ batch,
                                                            const float* __restrict__ w1,
                                                            const float* __restrict__ b1,
                                                            const float* __restrict__ w2,
                                                            const float* __restrict__ b2,
                                                            float* __restrict__ out) {
    int g = blockIdx.x;
    int tid = threadIdx.x;
    int start = lower_bound_batch(batch, g);
    int end = lower_bound_batch(batch, g + 1);
    int f = tid & 63;
    int grp = tid >> 6;
    float s0 = 0.f, s1 = 0.f, s2 = 0.f, s3 = 0.f;
    int n = start + grp;
    for (; n + 12 < end; n += 16) {
        s0 += h[(size_t)n * HDIM + f];
        s1 += h[(size_t)(n + 4) * HDIM + f];
        s2 += h[(size_t)(n + 8) * HDIM + f];
        s3 += h[(size_t)(n + 12) * HDIM + f];
    }
    for (; n < end; n += 4) s0 += h[(size_t)n * HDIM + f];
    float s = (s0 + s1) + (s2 + s3);
    __shared__ float red[4][64];
    __shared__ float repr[64], z[64], lg[NCLS];
    red[grp][f] = s;
    __syncthreads();
    if (grp == 0) {
        float tot = red[0][f] + red[1][f] + red[2][f] + red[3][f];
        int cnt = end - start;
        repr[f] = tot / (float)(cnt > 0 ? cnt : 1);
    }
    __syncthreads();
    if (tid < 64) {
        float acc = b1[tid];
#pragma unroll 8
        for (int k = 0; k < HDIM; ++k) acc += repr[k] * w1[k * HDIM + tid];
        z[tid] = fmaxf(acc, 0.0f);
    }
    __syncthreads();
    if (tid < NCLS) {
        float a2 = b2[tid];
#pragma unroll 8
        for (int k = 0; k < HDIM; ++k) a2 += z[k] * w2[k * NCLS + tid];
        lg[tid] = a2;
    }
    __syncthreads();
    if (tid < NCLS) {
        float m = -1e30f;
#pragma unroll
        for (int c = 0; c < NCLS; ++c) m = fmaxf(m, lg[c]);
        float sum = 0.0f;
#pragma unroll
        for (int c = 0; c < NCLS; ++c) sum += expf(lg[c] - m);
        out[g * NCLS + tid] = lg[tid] - m - logf(sum);
    }
}

// ---------------- host side ----------------

extern "C" void kernel_launch(void* const* d_in, const int* in_sizes, int n_in,
                              void* d_out, int out_size, void* d_ws, size_t ws_size,
                              hipStream_t stream) {
    const float* x        = (const float*)d_in[0];
    const float* conv_w   = (const float*)d_in[1];
    const float* conv_b   = (const float*)d_in[2];
    const float* bn_gamma = (const float*)d_in[3];
    const float* bn_beta  = (const float*)d_in[4];
    const float* bn_mean  = (const float*)d_in[5];
    const float* bn_var   = (const float*)d_in[6];
    const float* cls_w1   = (const float*)d_in[7];
    const float* cls_b1   = (const float*)d_in[8];
    const float* cls_w2   = (const float*)d_in[9];
    const float* cls_b2   = (const float*)d_in[10];
    const int* edge_index = (const int*)d_in[11];
    const int* batch      = (const int*)d_in[12];
    float* out = (float*)d_out;

    char* ws = (char*)d_ws;
    unsigned*       bhist   = (unsigned*)(ws);                  // 256 KiB
    unsigned*       bpos    = (unsigned*)(ws + (256u << 10));   // 256 KiB
    unsigned*       bsum    = (unsigned*)(ws + (512u << 10));   // 1 KiB
    unsigned*       carry   = (unsigned*)(ws + (513u << 10));   // 1 KiB
    float*          scb     = (float*)(ws + (514u << 10));      // 768 B
    float*          shb     = (float*)(ws + (515u << 10));      // 768 B
    float*          dis     = (float*)(ws + (768u << 10));      // 256 KiB
    unsigned*       offsets = (unsigned*)(ws + (1u << 20));     // 256 KiB + 4
    unsigned*       ebuf    = (unsigned*)(ws + (2u << 20));     // 4 MiB (packed dst<<16|src)
    unsigned short* srcs    = (unsigned short*)(ws + (6u << 20)); // 2 MiB
    __half*         hw16    = (__half*)(ws + (8u << 20));       // 8 MiB
    float*          h       = (float*)(ws + (16u << 20));       // 16 MiB

    // ---- preprocessing: deterministic two-level bucket sort into CSR ----
    hist_kernel<<<NPBLK, 256, 0, stream>>>(edge_index + N_EDGES, bhist);
    scan1_kernel<<<(NBUCKET * NPBLK) / 256, 256, 0, stream>>>(bhist, bpos, bsum);
    scan2_kernel<<<1, 256, 0, stream>>>(bsum, carry, conv_b, bn_gamma, bn_beta,
                                        bn_mean, bn_var, scb, shb);
    partition_kernel<<<NPBLK, 256, 0, stream>>>(edge_index, bpos, carry, ebuf);
    csr_kernel<<<NBUCKET, 256, 0, stream>>>(ebuf, bpos, carry, offsets, dis, srcs);

    // ---- layers: GEMM first (hw16 = (h@W)*dis in fp16), then feature-split gather ----
    for (int l = 0; l < NLAYER; ++l) {
        const float* hin = (l == 0) ? x : h;
        gemm_kernel<<<N_NODES / 64, 256, 0, stream>>>(hin, conv_w + l * HDIM * HDIM, dis, hw16);
        aggregate_kernel<<<dim3((N_NODES * 64) / 256, 2), 256, 0, stream>>>(
            hw16, dis, offsets, srcs, scb + l * HDIM, shb + l * HDIM, h, (l > 0) ? 1 : 0);
    }

    pool_classify_kernel<<<NGRAPH, 256, 0, stream>>>(h, batch, cls_w1, cls_b1, cls_w2, cls_b2, out);
}

// Round 12
// 185.865 us; speedup vs baseline: 1.3727x; 1.3727x over previous
//
#include <hip/hip_runtime.h>
#include <hip/hip_fp16.h>
#include <math.h>

#define N_NODES 65536
#define N_EDGES 1048576
#define HDIM 64
#define NCLS 10
#define NGRAPH 256
#define NLAYER 3
#define BN_EPS 1e-5f
#define NBUCKET 256     // nodes per bucket = 256, bucket = dst >> 8
#define NPBLK 256       // pass-1 blocks; edges per block = 4096

// ---------------- pass 1a: per-block bucket histogram ----------------

__global__ __launch_bounds__(256) void hist_kernel(const int* __restrict__ dst,
                                                   unsigned* __restrict__ bhist) {
    __shared__ unsigned hist[NBUCKET];
    int b = blockIdx.x, tid = threadIdx.x;
    hist[tid] = 0;
    __syncthreads();
    int base = b * 4096;
#pragma unroll
    for (int k = 0; k < 16; ++k) {
        int d = dst[base + k * 256 + tid];
        atomicAdd(&hist[d >> 8], 1u);
    }
    __syncthreads();
    bhist[tid * NPBLK + b] = hist[tid];  // bucket-major for lexicographic scan
}

// ---------------- pass 1b: exclusive scan over 64K (bucket, block) counts ----------------

__global__ __launch_bounds__(256) void scan1_kernel(const unsigned* __restrict__ in,
                                                    unsigned* __restrict__ out,
                                                    unsigned* __restrict__ bsum) {
    __shared__ unsigned lds[256];
    int t = threadIdx.x, b = blockIdx.x;
    unsigned v = in[b * 256 + t];
    lds[t] = v;
    __syncthreads();
#pragma unroll
    for (int off = 1; off < 256; off <<= 1) {
        unsigned add = (t >= off) ? lds[t - off] : 0u;
        __syncthreads();
        lds[t] += add;
        __syncthreads();
    }
    out[b * 256 + t] = lds[t] - v;  // exclusive within block
    if (t == 255) bsum[b] = lds[255];
}

// scan2 + BN-affine precompute fused
__global__ __launch_bounds__(256) void scan2_kernel(const unsigned* __restrict__ bsum,
                                                    unsigned* __restrict__ carry,
                                                    const float* __restrict__ bias,
                                                    const float* __restrict__ gamma,
                                                    const float* __restrict__ beta,
                                                    const float* __restrict__ mean,
                                                    const float* __restrict__ var,
                                                    float* __restrict__ scb,
                                                    float* __restrict__ shb) {
    __shared__ unsigned lds[256];
    int t = threadIdx.x;
    unsigned v = bsum[t];
    lds[t] = v;
    __syncthreads();
#pragma unroll
    for (int off = 1; off < 256; off <<= 1) {
        unsigned add = (t >= off) ? lds[t - off] : 0u;
        __syncthreads();
        lds[t] += add;
        __syncthreads();
    }
    carry[t] = lds[t] - v;  // exclusive
    if (t < NLAYER * HDIM) {
        float sc = gamma[t] * rsqrtf(var[t] + BN_EPS);
        scb[t] = sc;
        shb[t] = (bias[t] - mean[t]) * sc + beta[t];
    }
}

// ---------------- pass 1c: partition edges into coarse buckets (packed 16+16) ----------------

__global__ __launch_bounds__(256) void partition_kernel(const int* __restrict__ ei,
                                                        const unsigned* __restrict__ bpos,
                                                        const unsigned* __restrict__ carry,
                                                        unsigned* __restrict__ ebuf) {
    __shared__ unsigned cur[NBUCKET];
    int b = blockIdx.x, tid = threadIdx.x;
    cur[tid] = bpos[tid * NPBLK + b] + carry[tid];
    __syncthreads();
    int base = b * 4096;
#pragma unroll
    for (int k = 0; k < 16; ++k) {
        int e = base + k * 256 + tid;
        int s = ei[e];
        int d = ei[N_EDGES + e];
        unsigned slot = atomicAdd(&cur[d >> 8], 1u);
        ebuf[slot] = ((unsigned)d << 16) | (unsigned)s;
    }
}

// ---------------- pass 2: per-bucket exact CSR (block-private window) ----------------

__global__ __launch_bounds__(256) void csr_kernel(const unsigned* __restrict__ ebuf,
                                                  const unsigned* __restrict__ bpos,
                                                  const unsigned* __restrict__ carry,
                                                  unsigned* __restrict__ offsets,
                                                  float* __restrict__ dis,
                                                  unsigned short* __restrict__ srcs) {
    __shared__ unsigned hist[NBUCKET];
    __shared__ unsigned scn[NBUCKET];
    int B = blockIdx.x, tid = threadIdx.x;
    unsigned start = bpos[B * NPBLK] + carry[B];
    unsigned end = (B == NBUCKET - 1) ? N_EDGES : (bpos[(B + 1) * NPBLK] + carry[B + 1]);
    hist[tid] = 0;
    __syncthreads();
    for (unsigned e = start + tid; e < end; e += 256)
        atomicAdd(&hist[(ebuf[e] >> 16) & 255], 1u);
    __syncthreads();
    unsigned v = hist[tid];
    scn[tid] = v;
    __syncthreads();
#pragma unroll
    for (int off = 1; off < 256; off <<= 1) {
        unsigned add = (tid >= off) ? scn[tid - off] : 0u;
        __syncthreads();
        scn[tid] += add;
        __syncthreads();
    }
    unsigned gbase = start + scn[tid] - v;  // global CSR base for local node tid
    int node = B * 256 + tid;
    offsets[node] = gbase;
    dis[node] = rsqrtf((float)(v + 1u));
    if (B == NBUCKET - 1 && tid == 255) offsets[N_NODES] = N_EDGES;
    hist[tid] = gbase;  // reuse as global-slot cursor
    __syncthreads();
    for (unsigned e = start + tid; e < end; e += 256) {
        unsigned ed = ebuf[e];
        unsigned slot = atomicAdd(&hist[(ed >> 16) & 255], 1u);
        srcs[slot] = (unsigned short)(ed & 0xFFFFu);
    }
}

// ---------------- GEMM: hw16[n] = fp16((h @ W)[n] * dis[n]) ----------------
// hin is f32 (layer 0: x) or fp16 (h16), selected by use16; math stays f32.

__global__ __launch_bounds__(256) void gemm_kernel(const float* __restrict__ hin32,
                                                   const __half* __restrict__ hin16,
                                                   int use16,
                                                   const float* __restrict__ W,
                                                   const float* __restrict__ dis,
                                                   __half* __restrict__ hw16) {
    __shared__ float hs[64][68];
    __shared__ float ws[64 * 64];
    int tid = threadIdx.x;
    int row0 = blockIdx.x * 64;

    {
        const float4* Wv = (const float4*)W;
        float4* wsv = (float4*)ws;
#pragma unroll
        for (int i = 0; i < 4; ++i) wsv[tid + i * 256] = Wv[tid + i * 256];
    }
    if (use16) {
        const uint2* Hv = (const uint2*)(hin16 + (size_t)row0 * HDIM);
#pragma unroll
        for (int i = 0; i < 4; ++i) {
            int idx = tid + i * 256;            // uint2 (4 halves) index in 64x16 grid
            int r = idx >> 4;
            int c = (idx & 15) << 2;
            uint2 pk = Hv[idx];
            float2 lo = __half22float2(*(__half2*)&pk.x);
            float2 hi = __half22float2(*(__half2*)&pk.y);
            hs[r][c] = lo.x; hs[r][c + 1] = lo.y; hs[r][c + 2] = hi.x; hs[r][c + 3] = hi.y;
        }
    } else {
        const float4* Hv = (const float4*)(hin32 + (size_t)row0 * HDIM);
#pragma unroll
        for (int i = 0; i < 4; ++i) {
            int idx = tid + i * 256;
            int r = idx >> 4;
            int c = (idx & 15) << 2;
            *(float4*)&hs[r][c] = Hv[idx];
        }
    }
    __syncthreads();

    int tx = tid & 15, ty = tid >> 4;
    float acc[4][4] = {};
#pragma unroll
    for (int kq = 0; kq < 16; ++kq) {
        int k = kq * 4;
        float4 a[4], b[4];
#pragma unroll
        for (int i = 0; i < 4; ++i) a[i] = *(const float4*)&hs[ty * 4 + i][k];
#pragma unroll
        for (int kk = 0; kk < 4; ++kk) b[kk] = *(const float4*)&ws[(k + kk) * 64 + tx * 4];
#pragma unroll
        for (int kk = 0; kk < 4; ++kk) {
            float b0 = b[kk].x, b1 = b[kk].y, b2 = b[kk].z, b3 = b[kk].w;
#pragma unroll
            for (int i = 0; i < 4; ++i) {
                float av = (kk == 0) ? a[i].x : (kk == 1) ? a[i].y : (kk == 2) ? a[i].z : a[i].w;
                acc[i][0] += av * b0;
                acc[i][1] += av * b1;
                acc[i][2] += av * b2;
                acc[i][3] += av * b3;
            }
        }
    }

#pragma unroll
    for (int i = 0; i < 4; ++i) {
        int row = row0 + ty * 4 + i;
        float dd = dis[row];
        __half2 pa = __floats2half2_rn(acc[i][0] * dd, acc[i][1] * dd);
        __half2 pb = __floats2half2_rn(acc[i][2] * dd, acc[i][3] * dd);
        uint2 pk;
        pk.x = *(unsigned*)&pa;
        pk.y = *(unsigned*)&pb;
        *(uint2*)&hw16[(size_t)row * HDIM + tx * 4] = pk;
    }
}

// ---------------- aggregate + epilogue (R10 layout; h stored fp16) ----------------
// one wave per node; lanes = 8 edge-slots x 8 feature lanes (uint4 = 8 halves each).
// 16 edges in flight per wave.

__global__ __launch_bounds__(256) void aggregate_kernel(const __half* __restrict__ hw16,
                                                        const float* __restrict__ dis,
                                                        const unsigned* __restrict__ offsets,
                                                        const unsigned short* __restrict__ srcs,
                                                        const float* __restrict__ scb,
                                                        const float* __restrict__ shb,
                                                        __half* __restrict__ h16,
                                                        int has_res) {
    int n = (blockIdx.x * 256 + threadIdx.x) >> 6;
    int lane = threadIdx.x & 63;
    int eslot = lane >> 3;      // 0..7
    int fl = lane & 7;          // uint4 chunk within the 128B row
    int e0 = (int)offsets[n];
    int e1 = (int)offsets[n + 1];

    const uint4* hv = (const uint4*)hw16;  // 8 uint4 per row

    float4 accA = make_float4(0.f, 0.f, 0.f, 0.f);  // features fl*8+0..3
    float4 accB = make_float4(0.f, 0.f, 0.f, 0.f);  // features fl*8+4..7
    int e = e0 + eslot;
    for (; e + 8 < e1; e += 16) {
        int s0 = srcs[e];
        int s1 = srcs[e + 8];
        uint4 r0 = hv[(size_t)s0 * 8 + fl];
        uint4 r1 = hv[(size_t)s1 * 8 + fl];
        {
            float2 p0 = __half22float2(*(__half2*)&r0.x);
            float2 p1 = __half22float2(*(__half2*)&r0.y);
            float2 p2 = __half22float2(*(__half2*)&r0.z);
            float2 p3 = __half22float2(*(__half2*)&r0.w);
            accA.x += p0.x; accA.y += p0.y; accA.z += p1.x; accA.w += p1.y;
            accB.x += p2.x; accB.y += p2.y; accB.z += p3.x; accB.w += p3.y;
        }
        {
            float2 p0 = __half22float2(*(__half2*)&r1.x);
            float2 p1 = __half22float2(*(__half2*)&r1.y);
            float2 p2 = __half22float2(*(__half2*)&r1.z);
            float2 p3 = __half22float2(*(__half2*)&r1.w);
            accA.x += p0.x; accA.y += p0.y; accA.z += p1.x; accA.w += p1.y;
            accB.x += p2.x; accB.y += p2.y; accB.z += p3.x; accB.w += p3.y;
        }
    }
    if (e < e1) {
        int s0 = srcs[e];
        uint4 r0 = hv[(size_t)s0 * 8 + fl];
        float2 p0 = __half22float2(*(__half2*)&r0.x);
        float2 p1 = __half22float2(*(__half2*)&r0.y);
        float2 p2 = __half22float2(*(__half2*)&r0.z);
        float2 p3 = __half22float2(*(__half2*)&r0.w);
        accA.x += p0.x; accA.y += p0.y; accA.z += p1.x; accA.w += p1.y;
        accB.x += p2.x; accB.y += p2.y; accB.z += p3.x; accB.w += p3.y;
    }
    // reduce across the 8 edge slots (lane xor 8, 16, 32)
#pragma unroll
    for (int m = 8; m <= 32; m <<= 1) {
        accA.x += __shfl_xor(accA.x, m); accA.y += __shfl_xor(accA.y, m);
        accA.z += __shfl_xor(accA.z, m); accA.w += __shfl_xor(accA.w, m);
        accB.x += __shfl_xor(accB.x, m); accB.y += __shfl_xor(accB.y, m);
        accB.z += __shfl_xor(accB.z, m); accB.w += __shfl_xor(accB.w, m);
    }
    if (lane < 8) {
        // self-loop: + own row (hw16 already carries one dis factor)
        uint4 rs = hv[(size_t)n * 8 + fl];
        float2 p0 = __half22float2(*(__half2*)&rs.x);
        float2 p1 = __half22float2(*(__half2*)&rs.y);
        float2 p2 = __half22float2(*(__half2*)&rs.z);
        float2 p3 = __half22float2(*(__half2*)&rs.w);
        accA.x += p0.x; accA.y += p0.y; accA.z += p1.x; accA.w += p1.y;
        accB.x += p2.x; accB.y += p2.y; accB.z += p3.x; accB.w += p3.y;
        float d = dis[n];
        float4 scA = ((const float4*)scb)[fl * 2];
        float4 scB = ((const float4*)scb)[fl * 2 + 1];
        float4 shA = ((const float4*)shb)[fl * 2];
        float4 shB = ((const float4*)shb)[fl * 2 + 1];
        float o0 = fmaxf(accA.x * d * scA.x + shA.x, 0.0f);
        float o1 = fmaxf(accA.y * d * scA.y + shA.y, 0.0f);
        float o2 = fmaxf(accA.z * d * scA.z + shA.z, 0.0f);
        float o3 = fmaxf(accA.w * d * scA.w + shA.w, 0.0f);
        float o4 = fmaxf(accB.x * d * scB.x + shB.x, 0.0f);
        float o5 = fmaxf(accB.y * d * scB.y + shB.y, 0.0f);
        float o6 = fmaxf(accB.z * d * scB.z + shB.z, 0.0f);
        float o7 = fmaxf(accB.w * d * scB.w + shB.w, 0.0f);
        uint4* hp = (uint4*)&h16[(size_t)n * HDIM + fl * 8];
        if (has_res) {
            uint4 rr = *hp;
            float2 q0 = __half22float2(*(__half2*)&rr.x);
            float2 q1 = __half22float2(*(__half2*)&rr.y);
            float2 q2 = __half22float2(*(__half2*)&rr.z);
            float2 q3 = __half22float2(*(__half2*)&rr.w);
            o0 += q0.x; o1 += q0.y; o2 += q1.x; o3 += q1.y;
            o4 += q2.x; o5 += q2.y; o6 += q3.x; o7 += q3.y;
        }
        __half2 w0 = __floats2half2_rn(o0, o1);
        __half2 w1 = __floats2half2_rn(o2, o3);
        __half2 w2 = __floats2half2_rn(o4, o5);
        __half2 w3 = __floats2half2_rn(o6, o7);
        uint4 wo;
        wo.x = *(unsigned*)&w0; wo.y = *(unsigned*)&w1;
        wo.z = *(unsigned*)&w2; wo.w = *(unsigned*)&w3;
        *hp = wo;
    }
}

// ---------------- fused global mean pool + classifier (fp16 h) ----------------

__device__ __forceinline__ int lower_bound_batch(const int* __restrict__ batch, int val) {
    int lo = 0, hi = N_NODES;
    while (lo < hi) {
        int mid = (lo + hi) >> 1;
        if (batch[mid] < val) lo = mid + 1; else hi = mid;
    }
    return lo;
}

__global__ __launch_bounds__(256) void pool_classify_kernel(const __half* __restrict__ h16,
                                                            const int* __restrict__ batch,
                                                            const float* __restrict__ w1,
                                                            const float* __restrict__ b1,
                                                            const float* __restrict__ w2,
                                                            const float* __restrict__ b2,
                                                            float* __restrict__ out) {
    int g = blockIdx.x;
    int tid = threadIdx.x;
    int start = lower_bound_batch(batch, g);
    int end = lower_bound_batch(batch, g + 1);
    int f = tid & 63;
    int grp = tid >> 6;
    float s0 = 0.f, s1 = 0.f, s2 = 0.f, s3 = 0.f;
    int n = start + grp;
    for (; n + 12 < end; n += 16) {
        s0 += __half2float(h16[(size_t)n * HDIM + f]);
        s1 += __half2float(h16[(size_t)(n + 4) * HDIM + f]);
        s2 += __half2float(h16[(size_t)(n + 8) * HDIM + f]);
        s3 += __half2float(h16[(size_t)(n + 12) * HDIM + f]);
    }
    for (; n < end; n += 4) s0 += __half2float(h16[(size_t)n * HDIM + f]);
    float s = (s0 + s1) + (s2 + s3);
    __shared__ float red[4][64];
    __shared__ float repr[64], z[64], lg[NCLS];
    red[grp][f] = s;
    __syncthreads();
    if (grp == 0) {
        float tot = red[0][f] + red[1][f] + red[2][f] + red[3][f];
        int cnt = end - start;
        repr[f] = tot / (float)(cnt > 0 ? cnt : 1);
    }
    __syncthreads();
    if (tid < 64) {
        float acc = b1[tid];
#pragma unroll 8
        for (int k = 0; k < HDIM; ++k) acc += repr[k] * w1[k * HDIM + tid];
        z[tid] = fmaxf(acc, 0.0f);
    }
    __syncthreads();
    if (tid < NCLS) {
        float a2 = b2[tid];
#pragma unroll 8
        for (int k = 0; k < HDIM; ++k) a2 += z[k] * w2[k * NCLS + tid];
        lg[tid] = a2;
    }
    __syncthreads();
    if (tid < NCLS) {
        float m = -1e30f;
#pragma unroll
        for (int c = 0; c < NCLS; ++c) m = fmaxf(m, lg[c]);
        float sum = 0.0f;
#pragma unroll
        for (int c = 0; c < NCLS; ++c) sum += expf(lg[c] - m);
        out[g * NCLS + tid] = lg[tid] - m - logf(sum);
    }
}

// ---------------- host side ----------------

extern "C" void kernel_launch(void* const* d_in, const int* in_sizes, int n_in,
                              void* d_out, int out_size, void* d_ws, size_t ws_size,
                              hipStream_t stream) {
    const float* x        = (const float*)d_in[0];
    const float* conv_w   = (const float*)d_in[1];
    const float* conv_b   = (const float*)d_in[2];
    const float* bn_gamma = (const float*)d_in[3];
    const float* bn_beta  = (const float*)d_in[4];
    const float* bn_mean  = (const float*)d_in[5];
    const float* bn_var   = (const float*)d_in[6];
    const float* cls_w1   = (const float*)d_in[7];
    const float* cls_b1   = (const float*)d_in[8];
    const float* cls_w2   = (const float*)d_in[9];
    const float* cls_b2   = (const float*)d_in[10];
    const int* edge_index = (const int*)d_in[11];
    const int* batch      = (const int*)d_in[12];
    float* out = (float*)d_out;

    char* ws = (char*)d_ws;
    unsigned*       bhist   = (unsigned*)(ws);                  // 256 KiB
    unsigned*       bpos    = (unsigned*)(ws + (256u << 10));   // 256 KiB
    unsigned*       bsum    = (unsigned*)(ws + (512u << 10));   // 1 KiB
    unsigned*       carry   = (unsigned*)(ws + (513u << 10));   // 1 KiB
    float*          scb     = (float*)(ws + (514u << 10));      // 768 B
    float*          shb     = (float*)(ws + (515u << 10));      // 768 B
    float*          dis     = (float*)(ws + (768u << 10));      // 256 KiB
    unsigned*       offsets = (unsigned*)(ws + (1u << 20));     // 256 KiB + 4
    unsigned*       ebuf    = (unsigned*)(ws + (2u << 20));     // 4 MiB (packed dst<<16|src)
    unsigned short* srcs    = (unsigned short*)(ws + (6u << 20)); // 2 MiB
    __half*         hw16    = (__half*)(ws + (8u << 20));       // 8 MiB
    __half*         h16     = (__half*)(ws + (16u << 20));      // 8 MiB

    // ---- preprocessing: deterministic two-level bucket sort into CSR ----
    hist_kernel<<<NPBLK, 256, 0, stream>>>(edge_index + N_EDGES, bhist);
    scan1_kernel<<<(NBUCKET * NPBLK) / 256, 256, 0, stream>>>(bhist, bpos, bsum);
    scan2_kernel<<<1, 256, 0, stream>>>(bsum, carry, conv_b, bn_gamma, bn_beta,
                                        bn_mean, bn_var, scb, shb);
    partition_kernel<<<NPBLK, 256, 0, stream>>>(edge_index, bpos, carry, ebuf);
    csr_kernel<<<NBUCKET, 256, 0, stream>>>(ebuf, bpos, carry, offsets, dis, srcs);

    // ---- layers: GEMM first (hw16 = (h@W)*dis in fp16), then gather + epilogue ----
    for (int l = 0; l < NLAYER; ++l) {
        gemm_kernel<<<N_NODES / 64, 256, 0, stream>>>(
            x, h16, (l > 0) ? 1 : 0, conv_w + l * HDIM * HDIM, dis, hw16);
        aggregate_kernel<<<(N_NODES * 64) / 256, 256, 0, stream>>>(
            hw16, dis, offsets, srcs, scb + l * HDIM, shb + l * HDIM, h16, (l > 0) ? 1 : 0);
    }

    pool_classify_kernel<<<NGRAPH, 256, 0, stream>>>(h16, batch, cls_w1, cls_b1, cls_w2, cls_b2, out);
}

// Round 13
// 179.550 us; speedup vs baseline: 1.4210x; 1.0352x over previous
//
#include <hip/hip_runtime.h>
#include <hip/hip_fp16.h>
#include <math.h>

#define N_NODES 65536
#define N_EDGES 1048576
#define HDIM 64
#define NCLS 10
#define NGRAPH 256
#define NLAYER 3
#define BN_EPS 1e-5f
#define NBUCKET 256     // nodes per bucket = 256, bucket = dst >> 8
#define NPBLK 256       // pass-1 blocks; edges per block = 4096

// ---------------- pass 1a: per-block bucket histogram ----------------

__global__ __launch_bounds__(256) void hist_kernel(const int* __restrict__ dst,
                                                   unsigned* __restrict__ bhist) {
    __shared__ unsigned hist[NBUCKET];
    int b = blockIdx.x, tid = threadIdx.x;
    hist[tid] = 0;
    __syncthreads();
    int base = b * 4096;
#pragma unroll
    for (int k = 0; k < 16; ++k) {
        int d = dst[base + k * 256 + tid];
        atomicAdd(&hist[d >> 8], 1u);
    }
    __syncthreads();
    bhist[tid * NPBLK + b] = hist[tid];  // bucket-major for lexicographic scan
}

// ---------------- pass 1b: exclusive scan over 64K (bucket, block) counts ----------------

__global__ __launch_bounds__(256) void scan1_kernel(const unsigned* __restrict__ in,
                                                    unsigned* __restrict__ out,
                                                    unsigned* __restrict__ bsum) {
    __shared__ unsigned lds[256];
    int t = threadIdx.x, b = blockIdx.x;
    unsigned v = in[b * 256 + t];
    lds[t] = v;
    __syncthreads();
#pragma unroll
    for (int off = 1; off < 256; off <<= 1) {
        unsigned add = (t >= off) ? lds[t - off] : 0u;
        __syncthreads();
        lds[t] += add;
        __syncthreads();
    }
    out[b * 256 + t] = lds[t] - v;  // exclusive within block
    if (t == 255) bsum[b] = lds[255];
}

// scan2 + BN-affine precompute fused
__global__ __launch_bounds__(256) void scan2_kernel(const unsigned* __restrict__ bsum,
                                                    unsigned* __restrict__ carry,
                                                    const float* __restrict__ bias,
                                                    const float* __restrict__ gamma,
                                                    const float* __restrict__ beta,
                                                    const float* __restrict__ mean,
                                                    const float* __restrict__ var,
                                                    float* __restrict__ scb,
                                                    float* __restrict__ shb) {
    __shared__ unsigned lds[256];
    int t = threadIdx.x;
    unsigned v = bsum[t];
    lds[t] = v;
    __syncthreads();
#pragma unroll
    for (int off = 1; off < 256; off <<= 1) {
        unsigned add = (t >= off) ? lds[t - off] : 0u;
        __syncthreads();
        lds[t] += add;
        __syncthreads();
    }
    carry[t] = lds[t] - v;  // exclusive
    if (t < NLAYER * HDIM) {
        float sc = gamma[t] * rsqrtf(var[t] + BN_EPS);
        scb[t] = sc;
        shb[t] = (bias[t] - mean[t]) * sc + beta[t];
    }
}

// ---------------- pass 1c: partition edges into coarse buckets (packed 16+16) ----------------

__global__ __launch_bounds__(256) void partition_kernel(const int* __restrict__ ei,
                                                        const unsigned* __restrict__ bpos,
                                                        const unsigned* __restrict__ carry,
                                                        unsigned* __restrict__ ebuf) {
    __shared__ unsigned cur[NBUCKET];
    int b = blockIdx.x, tid = threadIdx.x;
    cur[tid] = bpos[tid * NPBLK + b] + carry[tid];
    __syncthreads();
    int base = b * 4096;
#pragma unroll
    for (int k = 0; k < 16; ++k) {
        int e = base + k * 256 + tid;
        int s = ei[e];
        int d = ei[N_EDGES + e];
        unsigned slot = atomicAdd(&cur[d >> 8], 1u);
        ebuf[slot] = ((unsigned)d << 16) | (unsigned)s;
    }
}

// ---------------- pass 2: per-bucket exact CSR (block-private window) ----------------

__global__ __launch_bounds__(256) void csr_kernel(const unsigned* __restrict__ ebuf,
                                                  const unsigned* __restrict__ bpos,
                                                  const unsigned* __restrict__ carry,
                                                  unsigned* __restrict__ offsets,
                                                  float* __restrict__ dis,
                                                  unsigned short* __restrict__ srcs) {
    __shared__ unsigned hist[NBUCKET];
    __shared__ unsigned scn[NBUCKET];
    int B = blockIdx.x, tid = threadIdx.x;
    unsigned start = bpos[B * NPBLK] + carry[B];
    unsigned end = (B == NBUCKET - 1) ? N_EDGES : (bpos[(B + 1) * NPBLK] + carry[B + 1]);
    hist[tid] = 0;
    __syncthreads();
    for (unsigned e = start + tid; e < end; e += 256)
        atomicAdd(&hist[(ebuf[e] >> 16) & 255], 1u);
    __syncthreads();
    unsigned v = hist[tid];
    scn[tid] = v;
    __syncthreads();
#pragma unroll
    for (int off = 1; off < 256; off <<= 1) {
        unsigned add = (tid >= off) ? scn[tid - off] : 0u;
        __syncthreads();
        scn[tid] += add;
        __syncthreads();
    }
    unsigned gbase = start + scn[tid] - v;  // global CSR base for local node tid
    int node = B * 256 + tid;
    offsets[node] = gbase;
    dis[node] = rsqrtf((float)(v + 1u));
    if (B == NBUCKET - 1 && tid == 255) offsets[N_NODES] = N_EDGES;
    hist[tid] = gbase;  // reuse as global-slot cursor
    __syncthreads();
    for (unsigned e = start + tid; e < end; e += 256) {
        unsigned ed = ebuf[e];
        unsigned slot = atomicAdd(&hist[(ed >> 16) & 255], 1u);
        srcs[slot] = (unsigned short)(ed & 0xFFFFu);
    }
}

// ---------------- GEMM: hw16[n] = fp16((h @ W)[n] * dis[n]) ----------------
// hin is f32 (layer 0: x) or fp16 (h16), selected by use16; math stays f32.

__global__ __launch_bounds__(256) void gemm_kernel(const float* __restrict__ hin32,
                                                   const __half* __restrict__ hin16,
                                                   int use16,
                                                   const float* __restrict__ W,
                                                   const float* __restrict__ dis,
                                                   __half* __restrict__ hw16) {
    __shared__ float hs[64][68];
    __shared__ float ws[64 * 64];
    int tid = threadIdx.x;
    int row0 = blockIdx.x * 64;

    {
        const float4* Wv = (const float4*)W;
        float4* wsv = (float4*)ws;
#pragma unroll
        for (int i = 0; i < 4; ++i) wsv[tid + i * 256] = Wv[tid + i * 256];
    }
    if (use16) {
        const uint2* Hv = (const uint2*)(hin16 + (size_t)row0 * HDIM);
#pragma unroll
        for (int i = 0; i < 4; ++i) {
            int idx = tid + i * 256;            // uint2 (4 halves) index in 64x16 grid
            int r = idx >> 4;
            int c = (idx & 15) << 2;
            uint2 pk = Hv[idx];
            float2 lo = __half22float2(*(__half2*)&pk.x);
            float2 hi = __half22float2(*(__half2*)&pk.y);
            hs[r][c] = lo.x; hs[r][c + 1] = lo.y; hs[r][c + 2] = hi.x; hs[r][c + 3] = hi.y;
        }
    } else {
        const float4* Hv = (const float4*)(hin32 + (size_t)row0 * HDIM);
#pragma unroll
        for (int i = 0; i < 4; ++i) {
            int idx = tid + i * 256;
            int r = idx >> 4;
            int c = (idx & 15) << 2;
            *(float4*)&hs[r][c] = Hv[idx];
        }
    }
    __syncthreads();

    int tx = tid & 15, ty = tid >> 4;
    float acc[4][4] = {};
#pragma unroll
    for (int kq = 0; kq < 16; ++kq) {
        int k = kq * 4;
        float4 a[4], b[4];
#pragma unroll
        for (int i = 0; i < 4; ++i) a[i] = *(const float4*)&hs[ty * 4 + i][k];
#pragma unroll
        for (int kk = 0; kk < 4; ++kk) b[kk] = *(const float4*)&ws[(k + kk) * 64 + tx * 4];
#pragma unroll
        for (int kk = 0; kk < 4; ++kk) {
            float b0 = b[kk].x, b1 = b[kk].y, b2 = b[kk].z, b3 = b[kk].w;
#pragma unroll
            for (int i = 0; i < 4; ++i) {
                float av = (kk == 0) ? a[i].x : (kk == 1) ? a[i].y : (kk == 2) ? a[i].z : a[i].w;
                acc[i][0] += av * b0;
                acc[i][1] += av * b1;
                acc[i][2] += av * b2;
                acc[i][3] += av * b3;
            }
        }
    }

#pragma unroll
    for (int i = 0; i < 4; ++i) {
        int row = row0 + ty * 4 + i;
        float dd = dis[row];
        __half2 pa = __floats2half2_rn(acc[i][0] * dd, acc[i][1] * dd);
        __half2 pb = __floats2half2_rn(acc[i][2] * dd, acc[i][3] * dd);
        uint2 pk;
        pk.x = *(unsigned*)&pa;
        pk.y = *(unsigned*)&pb;
        *(uint2*)&hw16[(size_t)row * HDIM + tx * 4] = pk;
    }
}

// ---------------- aggregate + epilogue ----------------
// one wave per node; lanes = 8 edge-slots x 8 feature lanes (uint4 = 8 halves each).
// src indices preloaded 64-at-a-time into registers; slots obtain them via __shfl,
// removing the srcs-load hop from the gather dependency chain.

#define ACC_ROW(r)                                              \
    do {                                                        \
        float2 p0 = __half22float2(*(__half2*)&(r).x);          \
        float2 p1 = __half22float2(*(__half2*)&(r).y);          \
        float2 p2 = __half22float2(*(__half2*)&(r).z);          \
        float2 p3 = __half22float2(*(__half2*)&(r).w);          \
        accA.x += p0.x; accA.y += p0.y; accA.z += p1.x; accA.w += p1.y; \
        accB.x += p2.x; accB.y += p2.y; accB.z += p3.x; accB.w += p3.y; \
    } while (0)

__global__ __launch_bounds__(256) void aggregate_kernel(const __half* __restrict__ hw16,
                                                        const float* __restrict__ dis,
                                                        const unsigned* __restrict__ offsets,
                                                        const unsigned short* __restrict__ srcs,
                                                        const float* __restrict__ scb,
                                                        const float* __restrict__ shb,
                                                        __half* __restrict__ h16,
                                                        int has_res) {
    int n = (blockIdx.x * 256 + threadIdx.x) >> 6;
    int lane = threadIdx.x & 63;
    int eslot = lane >> 3;      // 0..7
    int fl = lane & 7;          // uint4 chunk within the 128B row
    int e0 = (int)offsets[n];
    int e1 = (int)offsets[n + 1];
    int deg = e1 - e0;

    const uint4* hv = (const uint4*)hw16;  // 8 uint4 per row

    // coalesced preload of up to 64 src indices (one load instruction per wave)
    int sl = (int)srcs[min(e0 + lane, N_EDGES - 1)];
    // self-row gather issued early (independent of the edge loop)
    uint4 rs = hv[(size_t)n * 8 + fl];

    float4 accA = make_float4(0.f, 0.f, 0.f, 0.f);  // features fl*8+0..3
    float4 accB = make_float4(0.f, 0.f, 0.f, 0.f);  // features fl*8+4..7

    int degc = min(deg, 64);
    int nfull = degc >> 4;       // full iterations of 16 edges from the register file
    for (int it = 0; it < nfull; ++it) {
        int p = (it << 4) + eslot;
        int s0 = __shfl(sl, p);
        int s1 = __shfl(sl, p + 8);
        uint4 r0 = hv[(size_t)s0 * 8 + fl];
        uint4 r1 = hv[(size_t)s1 * 8 + fl];
        ACC_ROW(r0);
        ACC_ROW(r1);
    }
    {   // remainder within the preloaded 64 (0..15 edges)
        int p = (nfull << 4) + eslot;
        if (p < degc) {
            int s0 = __shfl(sl, p);
            uint4 r0 = hv[(size_t)s0 * 8 + fl];
            ACC_ROW(r0);
        }
        if (p + 8 < degc) {
            int s1 = __shfl(sl, p + 8);
            uint4 r1 = hv[(size_t)s1 * 8 + fl];
            ACC_ROW(r1);
        }
    }
    // degree > 64: direct-load tail (statistically never at mean deg 16, kept for correctness)
    for (int e = e0 + 64 + eslot; e < e1; e += 8) {
        int s0 = (int)srcs[e];
        uint4 r0 = hv[(size_t)s0 * 8 + fl];
        ACC_ROW(r0);
    }

    // reduce across the 8 edge slots (lane xor 8, 16, 32)
#pragma unroll
    for (int m = 8; m <= 32; m <<= 1) {
        accA.x += __shfl_xor(accA.x, m); accA.y += __shfl_xor(accA.y, m);
        accA.z += __shfl_xor(accA.z, m); accA.w += __shfl_xor(accA.w, m);
        accB.x += __shfl_xor(accB.x, m); accB.y += __shfl_xor(accB.y, m);
        accB.z += __shfl_xor(accB.z, m); accB.w += __shfl_xor(accB.w, m);
    }
    if (lane < 8) {
        // self-loop: + own row (hw16 already carries one dis factor)
        ACC_ROW(rs);
        float d = dis[n];
        float4 scA = ((const float4*)scb)[fl * 2];
        float4 scB = ((const float4*)scb)[fl * 2 + 1];
        float4 shA = ((const float4*)shb)[fl * 2];
        float4 shB = ((const float4*)shb)[fl * 2 + 1];
        float o0 = fmaxf(accA.x * d * scA.x + shA.x, 0.0f);
        float o1 = fmaxf(accA.y * d * scA.y + shA.y, 0.0f);
        float o2 = fmaxf(accA.z * d * scA.z + shA.z, 0.0f);
        float o3 = fmaxf(accA.w * d * scA.w + shA.w, 0.0f);
        float o4 = fmaxf(accB.x * d * scB.x + shB.x, 0.0f);
        float o5 = fmaxf(accB.y * d * scB.y + shB.y, 0.0f);
        float o6 = fmaxf(accB.z * d * scB.z + shB.z, 0.0f);
        float o7 = fmaxf(accB.w * d * scB.w + shB.w, 0.0f);
        uint4* hp = (uint4*)&h16[(size_t)n * HDIM + fl * 8];
        if (has_res) {
            uint4 rr = *hp;
            float2 q0 = __half22float2(*(__half2*)&rr.x);
            float2 q1 = __half22float2(*(__half2*)&rr.y);
            float2 q2 = __half22float2(*(__half2*)&rr.z);
            float2 q3 = __half22float2(*(__half2*)&rr.w);
            o0 += q0.x; o1 += q0.y; o2 += q1.x; o3 += q1.y;
            o4 += q2.x; o5 += q2.y; o6 += q3.x; o7 += q3.y;
        }
        __half2 w0 = __floats2half2_rn(o0, o1);
        __half2 w1 = __floats2half2_rn(o2, o3);
        __half2 w2 = __floats2half2_rn(o4, o5);
        __half2 w3 = __floats2half2_rn(o6, o7);
        uint4 wo;
        wo.x = *(unsigned*)&w0; wo.y = *(unsigned*)&w1;
        wo.z = *(unsigned*)&w2; wo.w = *(unsigned*)&w3;
        *hp = wo;
    }
}

// ---------------- fused global mean pool + classifier (fp16 h) ----------------

__device__ __forceinline__ int lower_bound_batch(const int* __restrict__ batch, int val) {
    int lo = 0, hi = N_NODES;
    while (lo < hi) {
        int mid = (lo + hi) >> 1;
        if (batch[mid] < val) lo = mid + 1; else hi = mid;
    }
    return lo;
}

__global__ __launch_bounds__(256) void pool_classify_kernel(const __half* __restrict__ h16,
                                                            const int* __restrict__ batch,
                                                            const float* __restrict__ w1,
                                                            const float* __restrict__ b1,
                                                            const float* __restrict__ w2,
                                                            const float* __restrict__ b2,
                                                            float* __restrict__ out) {
    int g = blockIdx.x;
    int tid = threadIdx.x;
    int start = lower_bound_batch(batch, g);
    int end = lower_bound_batch(batch, g + 1);
    int f = tid & 63;
    int grp = tid >> 6;
    float s0 = 0.f, s1 = 0.f, s2 = 0.f, s3 = 0.f;
    int n = start + grp;
    for (; n + 12 < end; n += 16) {
        s0 += __half2float(h16[(size_t)n * HDIM + f]);
        s1 += __half2float(h16[(size_t)(n + 4) * HDIM + f]);
        s2 += __half2float(h16[(size_t)(n + 8) * HDIM + f]);
        s3 += __half2float(h16[(size_t)(n + 12) * HDIM + f]);
    }
    for (; n < end; n += 4) s0 += __half2float(h16[(size_t)n * HDIM + f]);
    float s = (s0 + s1) + (s2 + s3);
    __shared__ float red[4][64];
    __shared__ float repr[64], z[64], lg[NCLS];
    red[grp][f] = s;
    __syncthreads();
    if (grp == 0) {
        float tot = red[0][f] + red[1][f] + red[2][f] + red[3][f];
        int cnt = end - start;
        repr[f] = tot / (float)(cnt > 0 ? cnt : 1);
    }
    __syncthreads();
    if (tid < 64) {
        float acc = b1[tid];
#pragma unroll 8
        for (int k = 0; k < HDIM; ++k) acc += repr[k] * w1[k * HDIM + tid];
        z[tid] = fmaxf(acc, 0.0f);
    }
    __syncthreads();
    if (tid < NCLS) {
        float a2 = b2[tid];
#pragma unroll 8
        for (int k = 0; k < HDIM; ++k) a2 += z[k] * w2[k * NCLS + tid];
        lg[tid] = a2;
    }
    __syncthreads();
    if (tid < NCLS) {
        float m = -1e30f;
#pragma unroll
        for (int c = 0; c < NCLS; ++c) m = fmaxf(m, lg[c]);
        float sum = 0.0f;
#pragma unroll
        for (int c = 0; c < NCLS; ++c) sum += expf(lg[c] - m);
        out[g * NCLS + tid] = lg[tid] - m - logf(sum);
    }
}

// ---------------- host side ----------------

extern "C" void kernel_launch(void* const* d_in, const int* in_sizes, int n_in,
                              void* d_out, int out_size, void* d_ws, size_t ws_size,
                              hipStream_t stream) {
    const float* x        = (const float*)d_in[0];
    const float* conv_w   = (const float*)d_in[1];
    const float* conv_b   = (const float*)d_in[2];
    const float* bn_gamma = (const float*)d_in[3];
    const float* bn_beta  = (const float*)d_in[4];
    const float* bn_mean  = (const float*)d_in[5];
    const float* bn_var   = (const float*)d_in[6];
    const float* cls_w1   = (const float*)d_in[7];
    const float* cls_b1   = (const float*)d_in[8];
    const float* cls_w2   = (const float*)d_in[9];
    const float* cls_b2   = (const float*)d_in[10];
    const int* edge_index = (const int*)d_in[11];
    const int* batch      = (const int*)d_in[12];
    float* out = (float*)d_out;

    char* ws = (char*)d_ws;
    unsigned*       bhist   = (unsigned*)(ws);                  // 256 KiB
    unsigned*       bpos    = (unsigned*)(ws + (256u << 10));   // 256 KiB
    unsigned*       bsum    = (unsigned*)(ws + (512u << 10));   // 1 KiB
    unsigned*       carry   = (unsigned*)(ws + (513u << 10));   // 1 KiB
    float*          scb     = (float*)(ws + (514u << 10));      // 768 B
    float*          shb     = (float*)(ws + (515u << 10));      // 768 B
    float*          dis     = (float*)(ws + (768u << 10));      // 256 KiB
    unsigned*       offsets = (unsigned*)(ws + (1u << 20));     // 256 KiB + 4
    unsigned*       ebuf    = (unsigned*)(ws + (2u << 20));     // 4 MiB (packed dst<<16|src)
    unsigned short* srcs    = (unsigned short*)(ws + (6u << 20)); // 2 MiB
    __half*         hw16    = (__half*)(ws + (8u << 20));       // 8 MiB
    __half*         h16     = (__half*)(ws + (16u << 20));      // 8 MiB

    // ---- preprocessing: deterministic two-level bucket sort into CSR ----
    hist_kernel<<<NPBLK, 256, 0, stream>>>(edge_index + N_EDGES, bhist);
    scan1_kernel<<<(NBUCKET * NPBLK) / 256, 256, 0, stream>>>(bhist, bpos, bsum);
    scan2_kernel<<<1, 256, 0, stream>>>(bsum, carry, conv_b, bn_gamma, bn_beta,
                                        bn_mean, bn_var, scb, shb);
    partition_kernel<<<NPBLK, 256, 0, stream>>>(edge_index, bpos, carry, ebuf);
    csr_kernel<<<NBUCKET, 256, 0, stream>>>(ebuf, bpos, carry, offsets, dis, srcs);

    // ---- layers: GEMM first (hw16 = (h@W)*dis in fp16), then gather + epilogue ----
    for (int l = 0; l < NLAYER; ++l) {
        gemm_kernel<<<N_NODES / 64, 256, 0, stream>>>(
            x, h16, (l > 0) ? 1 : 0, conv_w + l * HDIM * HDIM, dis, hw16);
        aggregate_kernel<<<(N_NODES * 64) / 256, 256, 0, stream>>>(
            hw16, dis, offsets, srcs, scb + l * HDIM, shb + l * HDIM, h16, (l > 0) ? 1 : 0);
    }

    pool_classify_kernel<<<NGRAPH, 256, 0, stream>>>(h16, batch, cls_w1, cls_b1, cls_w2, cls_b2, out);
}

// Round 14
// 170.387 us; speedup vs baseline: 1.4974x; 1.0538x over previous
//
#include <hip/hip_runtime.h>
#include <hip/hip_fp16.h>
#include <math.h>

#define N_NODES 65536
#define N_EDGES 1048576
#define HDIM 64
#define NCLS 10
#define NGRAPH 256
#define NLAYER 3
#define BN_EPS 1e-5f
#define NBUCKET 256     // nodes per bucket = 256, bucket = dst >> 8
#define NPBLK 256       // pass-1 blocks; edges per block = 4096

// ---------------- pass 1a: per-block bucket histogram ----------------

__global__ __launch_bounds__(256) void hist_kernel(const int* __restrict__ dst,
                                                   unsigned* __restrict__ bhist) {
    __shared__ unsigned hist[NBUCKET];
    int b = blockIdx.x, tid = threadIdx.x;
    hist[tid] = 0;
    __syncthreads();
    int base = b * 4096;
#pragma unroll
    for (int k = 0; k < 16; ++k) {
        int d = dst[base + k * 256 + tid];
        atomicAdd(&hist[d >> 8], 1u);
    }
    __syncthreads();
    bhist[tid * NPBLK + b] = hist[tid];  // bucket-major for lexicographic scan
}

// ---------------- pass 1b: exclusive scan over 64K (bucket, block) counts ----------------

__global__ __launch_bounds__(256) void scan1_kernel(const unsigned* __restrict__ in,
                                                    unsigned* __restrict__ out,
                                                    unsigned* __restrict__ bsum) {
    __shared__ unsigned lds[256];
    int t = threadIdx.x, b = blockIdx.x;
    unsigned v = in[b * 256 + t];
    lds[t] = v;
    __syncthreads();
#pragma unroll
    for (int off = 1; off < 256; off <<= 1) {
        unsigned add = (t >= off) ? lds[t - off] : 0u;
        __syncthreads();
        lds[t] += add;
        __syncthreads();
    }
    out[b * 256 + t] = lds[t] - v;  // exclusive within block
    if (t == 255) bsum[b] = lds[255];
}

// scan2 + BN-affine precompute fused
__global__ __launch_bounds__(256) void scan2_kernel(const unsigned* __restrict__ bsum,
                                                    unsigned* __restrict__ carry,
                                                    const float* __restrict__ bias,
                                                    const float* __restrict__ gamma,
                                                    const float* __restrict__ beta,
                                                    const float* __restrict__ mean,
                                                    const float* __restrict__ var,
                                                    float* __restrict__ scb,
                                                    float* __restrict__ shb) {
    __shared__ unsigned lds[256];
    int t = threadIdx.x;
    unsigned v = bsum[t];
    lds[t] = v;
    __syncthreads();
#pragma unroll
    for (int off = 1; off < 256; off <<= 1) {
        unsigned add = (t >= off) ? lds[t - off] : 0u;
        __syncthreads();
        lds[t] += add;
        __syncthreads();
    }
    carry[t] = lds[t] - v;  // exclusive
    if (t < NLAYER * HDIM) {
        float sc = gamma[t] * rsqrtf(var[t] + BN_EPS);
        scb[t] = sc;
        shb[t] = (bias[t] - mean[t]) * sc + beta[t];
    }
}

// ---------------- pass 1c: partition edges into coarse buckets (packed 16+16) ----------------

__global__ __launch_bounds__(256) void partition_kernel(const int* __restrict__ ei,
                                                        const unsigned* __restrict__ bpos,
                                                        const unsigned* __restrict__ carry,
                                                        unsigned* __restrict__ ebuf) {
    __shared__ unsigned cur[NBUCKET];
    int b = blockIdx.x, tid = threadIdx.x;
    cur[tid] = bpos[tid * NPBLK + b] + carry[tid];
    __syncthreads();
    int base = b * 4096;
#pragma unroll
    for (int k = 0; k < 16; ++k) {
        int e = base + k * 256 + tid;
        int s = ei[e];
        int d = ei[N_EDGES + e];
        unsigned slot = atomicAdd(&cur[d >> 8], 1u);
        ebuf[slot] = ((unsigned)d << 16) | (unsigned)s;
    }
}

// ---------------- pass 2: per-bucket exact CSR (block-private window) ----------------

__global__ __launch_bounds__(256) void csr_kernel(const unsigned* __restrict__ ebuf,
                                                  const unsigned* __restrict__ bpos,
                                                  const unsigned* __restrict__ carry,
                                                  unsigned* __restrict__ offsets,
                                                  float* __restrict__ dis,
                                                  unsigned short* __restrict__ srcs) {
    __shared__ unsigned hist[NBUCKET];
    __shared__ unsigned scn[NBUCKET];
    int B = blockIdx.x, tid = threadIdx.x;
    unsigned start = bpos[B * NPBLK] + carry[B];
    unsigned end = (B == NBUCKET - 1) ? N_EDGES : (bpos[(B + 1) * NPBLK] + carry[B + 1]);
    hist[tid] = 0;
    __syncthreads();
    for (unsigned e = start + tid; e < end; e += 256)
        atomicAdd(&hist[(ebuf[e] >> 16) & 255], 1u);
    __syncthreads();
    unsigned v = hist[tid];
    scn[tid] = v;
    __syncthreads();
#pragma unroll
    for (int off = 1; off < 256; off <<= 1) {
        unsigned add = (tid >= off) ? scn[tid - off] : 0u;
        __syncthreads();
        scn[tid] += add;
        __syncthreads();
    }
    unsigned gbase = start + scn[tid] - v;  // global CSR base for local node tid
    int node = B * 256 + tid;
    offsets[node] = gbase;
    dis[node] = rsqrtf((float)(v + 1u));
    if (B == NBUCKET - 1 && tid == 255) offsets[N_NODES] = N_EDGES;
    hist[tid] = gbase;  // reuse as global-slot cursor
    __syncthreads();
    for (unsigned e = start + tid; e < end; e += 256) {
        unsigned ed = ebuf[e];
        unsigned slot = atomicAdd(&hist[(ed >> 16) & 255], 1u);
        srcs[slot] = (unsigned short)(ed & 0xFFFFu);
    }
}

// ---------------- GEMM: hw16[n] = fp16((h @ W)[n] * dis[n]) ----------------
// hin is f32 (layer 0: x) or fp16 (h16), selected by use16; math stays f32.

__global__ __launch_bounds__(256) void gemm_kernel(const float* __restrict__ hin32,
                                                   const __half* __restrict__ hin16,
                                                   int use16,
                                                   const float* __restrict__ W,
                                                   const float* __restrict__ dis,
                                                   __half* __restrict__ hw16) {
    __shared__ float hs[64][68];
    __shared__ float ws[64 * 64];
    int tid = threadIdx.x;
    int row0 = blockIdx.x * 64;

    {
        const float4* Wv = (const float4*)W;
        float4* wsv = (float4*)ws;
#pragma unroll
        for (int i = 0; i < 4; ++i) wsv[tid + i * 256] = Wv[tid + i * 256];
    }
    if (use16) {
        const uint2* Hv = (const uint2*)(hin16 + (size_t)row0 * HDIM);
#pragma unroll
        for (int i = 0; i < 4; ++i) {
            int idx = tid + i * 256;            // uint2 (4 halves) index in 64x16 grid
            int r = idx >> 4;
            int c = (idx & 15) << 2;
            uint2 pk = Hv[idx];
            float2 lo = __half22float2(*(__half2*)&pk.x);
            float2 hi = __half22float2(*(__half2*)&pk.y);
            hs[r][c] = lo.x; hs[r][c + 1] = lo.y; hs[r][c + 2] = hi.x; hs[r][c + 3] = hi.y;
        }
    } else {
        const float4* Hv = (const float4*)(hin32 + (size_t)row0 * HDIM);
#pragma unroll
        for (int i = 0; i < 4; ++i) {
            int idx = tid + i * 256;
            int r = idx >> 4;
            int c = (idx & 15) << 2;
            *(float4*)&hs[r][c] = Hv[idx];
        }
    }
    __syncthreads();

    int tx = tid & 15, ty = tid >> 4;
    float acc[4][4] = {};
#pragma unroll
    for (int kq = 0; kq < 16; ++kq) {
        int k = kq * 4;
        float4 a[4], b[4];
#pragma unroll
        for (int i = 0; i < 4; ++i) a[i] = *(const float4*)&hs[ty * 4 + i][k];
#pragma unroll
        for (int kk = 0; kk < 4; ++kk) b[kk] = *(const float4*)&ws[(k + kk) * 64 + tx * 4];
#pragma unroll
        for (int kk = 0; kk < 4; ++kk) {
            float b0 = b[kk].x, b1 = b[kk].y, b2 = b[kk].z, b3 = b[kk].w;
#pragma unroll
            for (int i = 0; i < 4; ++i) {
                float av = (kk == 0) ? a[i].x : (kk == 1) ? a[i].y : (kk == 2) ? a[i].z : a[i].w;
                acc[i][0] += av * b0;
                acc[i][1] += av * b1;
                acc[i][2] += av * b2;
                acc[i][3] += av * b3;
            }
        }
    }

#pragma unroll
    for (int i = 0; i < 4; ++i) {
        int row = row0 + ty * 4 + i;
        float dd = dis[row];
        __half2 pa = __floats2half2_rn(acc[i][0] * dd, acc[i][1] * dd);
        __half2 pb = __floats2half2_rn(acc[i][2] * dd, acc[i][3] * dd);
        uint2 pk;
        pk.x = *(unsigned*)&pa;
        pk.y = *(unsigned*)&pb;
        *(uint2*)&hw16[(size_t)row * HDIM + tx * 4] = pk;
    }
}

// ---------------- aggregate + epilogue: TWO nodes per wave ----------------
// lanes = 8 edge-slots x 8 feature lanes (uint4 = 8 halves each) per node.
// Both nodes' gathers issue back-to-back: up to 32 lines in flight per wave.

#define ACC8(r, aA, aB)                                         \
    do {                                                        \
        float2 p0 = __half22float2(*(__half2*)&(r).x);          \
        float2 p1 = __half22float2(*(__half2*)&(r).y);          \
        float2 p2 = __half22float2(*(__half2*)&(r).z);          \
        float2 p3 = __half22float2(*(__half2*)&(r).w);          \
        aA.x += p0.x; aA.y += p0.y; aA.z += p1.x; aA.w += p1.y; \
        aB.x += p2.x; aB.y += p2.y; aB.z += p3.x; aB.w += p3.y; \
    } while (0)

__global__ __launch_bounds__(256) void aggregate_kernel(const __half* __restrict__ hw16,
                                                        const float* __restrict__ dis,
                                                        const unsigned* __restrict__ offsets,
                                                        const unsigned short* __restrict__ srcs,
                                                        const float* __restrict__ scb,
                                                        const float* __restrict__ shb,
                                                        __half* __restrict__ h16,
                                                        int has_res) {
    int wid = (blockIdx.x * 256 + threadIdx.x) >> 6;
    int n0 = wid << 1;
    int n1 = n0 + 1;
    int lane = threadIdx.x & 63;
    int eslot = lane >> 3;      // 0..7
    int fl = lane & 7;          // uint4 chunk within the 128B row

    int e0a = (int)offsets[n0];
    int mid = (int)offsets[n1];
    int e1b = (int)offsets[n1 + 1];
    int degA = mid - e0a;
    int degB = e1b - mid;

    const uint4* hv = (const uint4*)hw16;  // 8 uint4 per row

    // coalesced preload of up to 64 src indices per node
    int slA = (int)srcs[min(e0a + lane, N_EDGES - 1)];
    int slB = (int)srcs[min(mid + lane, N_EDGES - 1)];
    // self rows issued early
    uint4 rsa = hv[(size_t)n0 * 8 + fl];
    uint4 rsb = hv[(size_t)n1 * 8 + fl];

    float4 aA0 = make_float4(0.f, 0.f, 0.f, 0.f), aA1 = make_float4(0.f, 0.f, 0.f, 0.f);
    float4 aB0 = make_float4(0.f, 0.f, 0.f, 0.f), aB1 = make_float4(0.f, 0.f, 0.f, 0.f);

    int degcA = min(degA, 64), degcB = min(degB, 64);
    int nfA = degcA >> 4, nfB = degcB >> 4;
    int nmax = (nfA > nfB) ? nfA : nfB;
    for (int it = 0; it < nmax; ++it) {
        int p = (it << 4) + eslot;
        uint4 r0a, r1a, r0b, r1b;
        bool da = it < nfA, db = it < nfB;
        if (da) {
            int s0 = __shfl(slA, p);
            int s1 = __shfl(slA, p + 8);
            r0a = hv[(size_t)s0 * 8 + fl];
            r1a = hv[(size_t)s1 * 8 + fl];
        }
        if (db) {
            int s0 = __shfl(slB, p);
            int s1 = __shfl(slB, p + 8);
            r0b = hv[(size_t)s0 * 8 + fl];
            r1b = hv[(size_t)s1 * 8 + fl];
        }
        if (da) { ACC8(r0a, aA0, aA1); ACC8(r1a, aA0, aA1); }
        if (db) { ACC8(r0b, aB0, aB1); ACC8(r1b, aB0, aB1); }
    }
    {   // remainders within the preloaded 64
        int pA = (nfA << 4) + eslot;
        int pB = (nfB << 4) + eslot;
        uint4 r0a, r1a, r0b, r1b;
        bool a0 = pA < degcA, a1 = pA + 8 < degcA;
        bool b0 = pB < degcB, b1 = pB + 8 < degcB;
        if (a0) r0a = hv[(size_t)__shfl(slA, pA) * 8 + fl];
        if (a1) r1a = hv[(size_t)__shfl(slA, pA + 8) * 8 + fl];
        if (b0) r0b = hv[(size_t)__shfl(slB, pB) * 8 + fl];
        if (b1) r1b = hv[(size_t)__shfl(slB, pB + 8) * 8 + fl];
        if (a0) ACC8(r0a, aA0, aA1);
        if (a1) ACC8(r1a, aA0, aA1);
        if (b0) ACC8(r0b, aB0, aB1);
        if (b1) ACC8(r1b, aB0, aB1);
    }
    // degree > 64 tails (statistically never at mean deg 16, kept for correctness)
    for (int e = e0a + 64 + eslot; e < mid; e += 8) {
        uint4 r = hv[(size_t)srcs[e] * 8 + fl];
        ACC8(r, aA0, aA1);
    }
    for (int e = mid + 64 + eslot; e < e1b; e += 8) {
        uint4 r = hv[(size_t)srcs[e] * 8 + fl];
        ACC8(r, aB0, aB1);
    }

    // reduce across the 8 edge slots (lane xor 8, 16, 32); fl bits untouched
#pragma unroll
    for (int m = 8; m <= 32; m <<= 1) {
        aA0.x += __shfl_xor(aA0.x, m); aA0.y += __shfl_xor(aA0.y, m);
        aA0.z += __shfl_xor(aA0.z, m); aA0.w += __shfl_xor(aA0.w, m);
        aA1.x += __shfl_xor(aA1.x, m); aA1.y += __shfl_xor(aA1.y, m);
        aA1.z += __shfl_xor(aA1.z, m); aA1.w += __shfl_xor(aA1.w, m);
        aB0.x += __shfl_xor(aB0.x, m); aB0.y += __shfl_xor(aB0.y, m);
        aB0.z += __shfl_xor(aB0.z, m); aB0.w += __shfl_xor(aB0.w, m);
        aB1.x += __shfl_xor(aB1.x, m); aB1.y += __shfl_xor(aB1.y, m);
        aB1.z += __shfl_xor(aB1.z, m); aB1.w += __shfl_xor(aB1.w, m);
    }
    if (lane < 16) {
        // lanes 0-7: node0, lanes 8-15: node1 (every lane holds all reduced sums)
        int node = (lane < 8) ? n0 : n1;
        float4 vA = (lane < 8) ? aA0 : aB0;
        float4 vB = (lane < 8) ? aA1 : aB1;
        uint4 rs = (lane < 8) ? rsa : rsb;
        // self-loop: + own row (hw16 already carries one dis factor)
        ACC8(rs, vA, vB);
        float d = dis[node];
        float4 scA = ((const float4*)scb)[fl * 2];
        float4 scB = ((const float4*)scb)[fl * 2 + 1];
        float4 shA = ((const float4*)shb)[fl * 2];
        float4 shB = ((const float4*)shb)[fl * 2 + 1];
        float o0 = fmaxf(vA.x * d * scA.x + shA.x, 0.0f);
        float o1 = fmaxf(vA.y * d * scA.y + shA.y, 0.0f);
        float o2 = fmaxf(vA.z * d * scA.z + shA.z, 0.0f);
        float o3 = fmaxf(vA.w * d * scA.w + shA.w, 0.0f);
        float o4 = fmaxf(vB.x * d * scB.x + shB.x, 0.0f);
        float o5 = fmaxf(vB.y * d * scB.y + shB.y, 0.0f);
        float o6 = fmaxf(vB.z * d * scB.z + shB.z, 0.0f);
        float o7 = fmaxf(vB.w * d * scB.w + shB.w, 0.0f);
        uint4* hp = (uint4*)&h16[(size_t)node * HDIM + fl * 8];
        if (has_res) {
            uint4 rr = *hp;
            float2 q0 = __half22float2(*(__half2*)&rr.x);
            float2 q1 = __half22float2(*(__half2*)&rr.y);
            float2 q2 = __half22float2(*(__half2*)&rr.z);
            float2 q3 = __half22float2(*(__half2*)&rr.w);
            o0 += q0.x; o1 += q0.y; o2 += q1.x; o3 += q1.y;
            o4 += q2.x; o5 += q2.y; o6 += q3.x; o7 += q3.y;
        }
        __half2 w0 = __floats2half2_rn(o0, o1);
        __half2 w1 = __floats2half2_rn(o2, o3);
        __half2 w2 = __floats2half2_rn(o4, o5);
        __half2 w3 = __floats2half2_rn(o6, o7);
        uint4 wo;
        wo.x = *(unsigned*)&w0; wo.y = *(unsigned*)&w1;
        wo.z = *(unsigned*)&w2; wo.w = *(unsigned*)&w3;
        *hp = wo;
    }
}

// ---------------- fused global mean pool + classifier (fp16 h) ----------------

__device__ __forceinline__ int lower_bound_batch(const int* __restrict__ batch, int val) {
    int lo = 0, hi = N_NODES;
    while (lo < hi) {
        int mid = (lo + hi) >> 1;
        if (batch[mid] < val) lo = mid + 1; else hi = mid;
    }
    return lo;
}

__global__ __launch_bounds__(256) void pool_classify_kernel(const __half* __restrict__ h16,
                                                            const int* __restrict__ batch,
                                                            const float* __restrict__ w1,
                                                            const float* __restrict__ b1,
                                                            const float* __restrict__ w2,
                                                            const float* __restrict__ b2,
                                                            float* __restrict__ out) {
    int g = blockIdx.x;
    int tid = threadIdx.x;
    int start = lower_bound_batch(batch, g);
    int end = lower_bound_batch(batch, g + 1);
    int f = tid & 63;
    int grp = tid >> 6;
    float s0 = 0.f, s1 = 0.f, s2 = 0.f, s3 = 0.f;
    int n = start + grp;
    for (; n + 12 < end; n += 16) {
        s0 += __half2float(h16[(size_t)n * HDIM + f]);
        s1 += __half2float(h16[(size_t)(n + 4) * HDIM + f]);
        s2 += __half2float(h16[(size_t)(n + 8) * HDIM + f]);
        s3 += __half2float(h16[(size_t)(n + 12) * HDIM + f]);
    }
    for (; n < end; n += 4) s0 += __half2float(h16[(size_t)n * HDIM + f]);
    float s = (s0 + s1) + (s2 + s3);
    __shared__ float red[4][64];
    __shared__ float repr[64], z[64], lg[NCLS];
    red[grp][f] = s;
    __syncthreads();
    if (grp == 0) {
        float tot = red[0][f] + red[1][f] + red[2][f] + red[3][f];
        int cnt = end - start;
        repr[f] = tot / (float)(cnt > 0 ? cnt : 1);
    }
    __syncthreads();
    if (tid < 64) {
        float acc = b1[tid];
#pragma unroll 8
        for (int k = 0; k < HDIM; ++k) acc += repr[k] * w1[k * HDIM + tid];
        z[tid] = fmaxf(acc, 0.0f);
    }
    __syncthreads();
    if (tid < NCLS) {
        float a2 = b2[tid];
#pragma unroll 8
        for (int k = 0; k < HDIM; ++k) a2 += z[k] * w2[k * NCLS + tid];
        lg[tid] = a2;
    }
    __syncthreads();
    if (tid < NCLS) {
        float m = -1e30f;
#pragma unroll
        for (int c = 0; c < NCLS; ++c) m = fmaxf(m, lg[c]);
        float sum = 0.0f;
#pragma unroll
        for (int c = 0; c < NCLS; ++c) sum += expf(lg[c] - m);
        out[g * NCLS + tid] = lg[tid] - m - logf(sum);
    }
}

// ---------------- host side ----------------

extern "C" void kernel_launch(void* const* d_in, const int* in_sizes, int n_in,
                              void* d_out, int out_size, void* d_ws, size_t ws_size,
                              hipStream_t stream) {
    const float* x        = (const float*)d_in[0];
    const float* conv_w   = (const float*)d_in[1];
    const float* conv_b   = (const float*)d_in[2];
    const float* bn_gamma = (const float*)d_in[3];
    const float* bn_beta  = (const float*)d_in[4];
    const float* bn_mean  = (const float*)d_in[5];
    const float* bn_var   = (const float*)d_in[6];
    const float* cls_w1   = (const float*)d_in[7];
    const float* cls_b1   = (const float*)d_in[8];
    const float* cls_w2   = (const float*)d_in[9];
    const float* cls_b2   = (const float*)d_in[10];
    const int* edge_index = (const int*)d_in[11];
    const int* batch      = (const int*)d_in[12];
    float* out = (float*)d_out;

    char* ws = (char*)d_ws;
    unsigned*       bhist   = (unsigned*)(ws);                  // 256 KiB
    unsigned*       bpos    = (unsigned*)(ws + (256u << 10));   // 256 KiB
    unsigned*       bsum    = (unsigned*)(ws + (512u << 10));   // 1 KiB
    unsigned*       carry   = (unsigned*)(ws + (513u << 10));   // 1 KiB
    float*          scb     = (float*)(ws + (514u << 10));      // 768 B
    float*          shb     = (float*)(ws + (515u << 10));      // 768 B
    float*          dis     = (float*)(ws + (768u << 10));      // 256 KiB
    unsigned*       offsets = (unsigned*)(ws + (1u << 20));     // 256 KiB + 4
    unsigned*       ebuf    = (unsigned*)(ws + (2u << 20));     // 4 MiB (packed dst<<16|src)
    unsigned short* srcs    = (unsigned short*)(ws + (6u << 20)); // 2 MiB
    __half*         hw16    = (__half*)(ws + (8u << 20));       // 8 MiB
    __half*         h16     = (__half*)(ws + (16u << 20));      // 8 MiB

    // ---- preprocessing: deterministic two-level bucket sort into CSR ----
    hist_kernel<<<NPBLK, 256, 0, stream>>>(edge_index + N_EDGES, bhist);
    scan1_kernel<<<(NBUCKET * NPBLK) / 256, 256, 0, stream>>>(bhist, bpos, bsum);
    scan2_kernel<<<1, 256, 0, stream>>>(bsum, carry, conv_b, bn_gamma, bn_beta,
                                        bn_mean, bn_var, scb, shb);
    partition_kernel<<<NPBLK, 256, 0, stream>>>(edge_index, bpos, carry, ebuf);
    csr_kernel<<<NBUCKET, 256, 0, stream>>>(ebuf, bpos, carry, offsets, dis, srcs);

    // ---- layers: GEMM first (hw16 = (h@W)*dis in fp16), then gather + epilogue ----
    for (int l = 0; l < NLAYER; ++l) {
        gemm_kernel<<<N_NODES / 64, 256, 0, stream>>>(
            x, h16, (l > 0) ? 1 : 0, conv_w + l * HDIM * HDIM, dis, hw16);
        aggregate_kernel<<<(N_NODES / 2 * 64) / 256, 256, 0, stream>>>(
            hw16, dis, offsets, srcs, scb + l * HDIM, shb + l * HDIM, h16, (l > 0) ? 1 : 0);
    }

    pool_classify_kernel<<<NGRAPH, 256, 0, stream>>>(h16, batch, cls_w1, cls_b1, cls_w2, cls_b2, out);
}